// Round 1
// baseline (454.677 us; speedup 1.0000x reference)
//
#include <hip/hip_runtime.h>
#include <hip/hip_bf16.h>
#include <stdint.h>
#include <cmath>

// IDXST_IDCT on MI355X: y = S · x · C^T with
//   C[v,q] = cos(pi*q*(2v+1)/(2N)),  S[u,p] = sin(pi*p*(2u+1)/(2M))
// Implemented as two bf16-MFMA bt-GEMMs (C[m,n] = sum_k A[m,k]*Bt[n,k]):
//   stage1: tT[v,p] = sum_q C[v,q] * xb[p,q]     (A=C,  Bt=xb,  out bf16)
//   stage2: y[u,v]  = sum_p S[u,p] * tT[v,p]     (A=S,  Bt=tT,  out fp32)

typedef __attribute__((ext_vector_type(4))) float f32x4;
typedef __attribute__((ext_vector_type(8))) unsigned short u16x8;
typedef __attribute__((ext_vector_type(8))) __bf16 bf16x8;

__device__ __forceinline__ unsigned short f2bf(float f) {
  union { float f; unsigned u; } v; v.f = f;
  unsigned u = v.u + 0x7fffu + ((v.u >> 16) & 1u);  // RNE
  return (unsigned short)(u >> 16);
}

// ---- stage 0a: fp32 -> bf16 convert (8 elems/thread) ----
__global__ void convert_kernel(const f32x4* __restrict__ x,
                               u16x8* __restrict__ out, int n8) {
  int idx = blockIdx.x * blockDim.x + threadIdx.x;
  if (idx >= n8) return;
  f32x4 a = x[2 * idx];
  f32x4 b = x[2 * idx + 1];
  u16x8 o;
  o[0] = f2bf(a[0]); o[1] = f2bf(a[1]); o[2] = f2bf(a[2]); o[3] = f2bf(a[3]);
  o[4] = f2bf(b[0]); o[5] = f2bf(b[1]); o[6] = f2bf(b[2]); o[7] = f2bf(b[3]);
  out[idx] = o;
}

// ---- stage 0b: generate transform matrices (M==N assumed) ----
// angle = pi * ((j*(2i+1)) mod 4N) / (2N); product < 2^25 so exact in u32.
__global__ void gen_mats_kernel(unsigned short* __restrict__ Ccos,
                                unsigned short* __restrict__ S,
                                int colMask, int shift, unsigned mask4N,
                                float angScale) {
  int idx = blockIdx.x * blockDim.x + threadIdx.x;
  int i = idx >> shift;       // row
  int j = idx & colMask;      // col
  unsigned r = ((unsigned)j * (unsigned)(2 * i + 1)) & mask4N;
  float ang = (float)r * angScale;
  float s, c;
  __sincosf(ang, &s, &c);
  Ccos[idx] = f2bf(c);
  S[idx] = f2bf(s);
}

// ---- bt-GEMM: C[m,n] = sum_k A[m,k] * Bt[n,k], bf16 in, fp32 acc ----
// BM=BN=128, BK=32, 256 threads (4 waves, 2x2 wave grid, 64x64 per wave).
template <bool OUT_BF16>
__global__ __launch_bounds__(256, 2) void btgemm_kernel(
    const unsigned short* __restrict__ A,   // [Mdim x K] bf16 row-major
    const unsigned short* __restrict__ Bt,  // [Ndim x K] bf16 row-major
    void* __restrict__ C,                   // [Mdim x Ndim]
    int Ndim, int K) {
  __shared__ unsigned short As[128 * 32];
  __shared__ unsigned short Bs[128 * 32];

  const int tid = threadIdx.x;
  const int m0 = blockIdx.y * 128;
  const int n0 = blockIdx.x * 128;

  const int wave = tid >> 6;
  const int lane = tid & 63;
  const int wm = (wave & 1) * 64;
  const int wn = (wave >> 1) * 64;
  const int l16 = lane & 15;
  const int quad = lane >> 4;

  f32x4 acc[4][4];
#pragma unroll
  for (int i = 0; i < 4; i++)
#pragma unroll
    for (int j = 0; j < 4; j++) acc[i][j] = f32x4{0.f, 0.f, 0.f, 0.f};

  // staging: 512 16B-chunks per 8KB tile; thread t handles chunks t, t+256
  const int r0 = tid >> 2;            // row 0..63 (and +64)
  const int c0 = (tid & 3) * 8;       // bf16 element offset within row

  const unsigned short* Abase = A + (size_t)m0 * K;
  const unsigned short* Bbase = Bt + (size_t)n0 * K;

  for (int k0 = 0; k0 < K; k0 += 32) {
    u16x8 a0 = *(const u16x8*)(Abase + (size_t)r0 * K + k0 + c0);
    u16x8 a1 = *(const u16x8*)(Abase + (size_t)(r0 + 64) * K + k0 + c0);
    u16x8 b0 = *(const u16x8*)(Bbase + (size_t)r0 * K + k0 + c0);
    u16x8 b1 = *(const u16x8*)(Bbase + (size_t)(r0 + 64) * K + k0 + c0);
    __syncthreads();  // previous iter's LDS reads done before overwrite
    *(u16x8*)(As + r0 * 32 + c0) = a0;
    *(u16x8*)(As + (r0 + 64) * 32 + c0) = a1;
    *(u16x8*)(Bs + r0 * 32 + c0) = b0;
    *(u16x8*)(Bs + (r0 + 64) * 32 + c0) = b1;
    __syncthreads();

    bf16x8 af[4], bfr[4];
#pragma unroll
    for (int i = 0; i < 4; i++) {
      af[i]  = *(const bf16x8*)(As + (wm + i * 16 + l16) * 32 + quad * 8);
      bfr[i] = *(const bf16x8*)(Bs + (wn + i * 16 + l16) * 32 + quad * 8);
    }
#pragma unroll
    for (int i = 0; i < 4; i++)
#pragma unroll
      for (int j = 0; j < 4; j++)
        acc[i][j] = __builtin_amdgcn_mfma_f32_16x16x32_bf16(af[i], bfr[j],
                                                            acc[i][j], 0, 0, 0);
  }

  // epilogue: D row = quad*4 + reg, col = lane&15
#pragma unroll
  for (int i = 0; i < 4; i++) {
#pragma unroll
    for (int j = 0; j < 4; j++) {
      int col = n0 + wn + j * 16 + l16;
      int rowb = m0 + wm + i * 16 + quad * 4;
#pragma unroll
      for (int r = 0; r < 4; r++) {
        float v = acc[i][j][r];
        if (OUT_BF16)
          ((unsigned short*)C)[(size_t)(rowb + r) * Ndim + col] = f2bf(v);
        else
          ((float*)C)[(size_t)(rowb + r) * Ndim + col] = v;
      }
    }
  }
}

extern "C" void kernel_launch(void* const* d_in, const int* in_sizes, int n_in,
                              void* d_out, int out_size, void* d_ws,
                              size_t ws_size, hipStream_t stream) {
  const float* x = (const float*)d_in[0];
  const int M = in_sizes[1] / 2;  // expkM is [M,2]
  const int N = in_sizes[2] / 2;  // expkN is [N,2]
  const size_t MN = (size_t)M * N;

  // workspace: xb | Ccos | S | tT  (bf16 each) = 4 * M*N*2 bytes = 128 MB
  unsigned short* xb   = (unsigned short*)d_ws;
  unsigned short* Ccos = xb + MN;
  unsigned short* S    = Ccos + MN;
  unsigned short* tT   = S + MN;

  // 0a: x -> bf16
  int n8 = (int)(MN / 8);
  convert_kernel<<<(n8 + 255) / 256, 256, 0, stream>>>((const f32x4*)x,
                                                       (u16x8*)xb, n8);

  // 0b: transform matrices (M == N == 4096 here; same angle -> one sincos)
  int shift = 0;
  while ((1 << shift) < N) shift++;
  float angScale = (float)(3.14159265358979323846 / (2.0 * (double)N));
  gen_mats_kernel<<<(int)(MN / 256), 256, 0, stream>>>(
      Ccos, S, N - 1, shift, (unsigned)(4 * N - 1), angScale);

  // stage 1: tT[v,p] = sum_q C[v,q]*xb[p,q]   -> bf16 [N x M]
  dim3 blk(256);
  dim3 g1(M / 128, N / 128);
  btgemm_kernel<true><<<g1, blk, 0, stream>>>(Ccos, xb, tT, M, N);

  // stage 2: y[u,v] = sum_p S[u,p]*tT[v,p]    -> fp32 [M x N]
  dim3 g2(N / 128, M / 128);
  btgemm_kernel<false><<<g2, blk, 0, stream>>>(S, tT, d_out, N, M);
}

// Round 2
// 416.322 us; speedup vs baseline: 1.0921x; 1.0921x over previous
//
#include <hip/hip_runtime.h>
#include <hip/hip_bf16.h>
#include <stdint.h>
#include <cmath>

// IDXST_IDCT on MI355X: y = S · x · C^T with
//   C[v,q] = cos(pi*q*(2v+1)/(2N)),  S[u,p] = sin(pi*p*(2u+1)/(2M))
// Two bf16-MFMA bt-GEMMs (C[m,n] = sum_k A[m,k]*Bt[n,k]):
//   stage1: tT[v,p] = sum_q C[v,q] * xb[p,q]     (A=C,  Bt=xb,  out bf16)
//   stage2: y[u,v]  = sum_p S[u,p] * tT[v,p]     (A=S,  Bt=tT,  out fp32)

typedef __attribute__((ext_vector_type(4))) float f32x4;
typedef __attribute__((ext_vector_type(8))) unsigned short u16x8;
typedef __attribute__((ext_vector_type(8))) __bf16 bf16x8;

__device__ __forceinline__ unsigned short f2bf(float f) {
  union { float f; unsigned u; } v; v.f = f;
  unsigned u = v.u + 0x7fffu + ((v.u >> 16) & 1u);  // RNE
  return (unsigned short)(u >> 16);
}

// ---- stage 0a: fp32 -> bf16 convert (8 elems/thread) ----
__global__ void convert_kernel(const f32x4* __restrict__ x,
                               u16x8* __restrict__ out, int n8) {
  int idx = blockIdx.x * blockDim.x + threadIdx.x;
  if (idx >= n8) return;
  f32x4 a = x[2 * idx];
  f32x4 b = x[2 * idx + 1];
  u16x8 o;
  o[0] = f2bf(a[0]); o[1] = f2bf(a[1]); o[2] = f2bf(a[2]); o[3] = f2bf(a[3]);
  o[4] = f2bf(b[0]); o[5] = f2bf(b[1]); o[6] = f2bf(b[2]); o[7] = f2bf(b[3]);
  out[idx] = o;
}

// ---- stage 0b: generate transform matrices, 8 cols/thread ----
// angle = pi * ((j*(2i+1)) mod 4N) / (2N); products < 2^25 so exact in u32.
__global__ void gen_mats_kernel(u16x8* __restrict__ Ccos,
                                u16x8* __restrict__ S,
                                int colMask, int shift, unsigned mask4N,
                                float angScale) {
  int idx = blockIdx.x * blockDim.x + threadIdx.x;
  int flat = idx * 8;
  int i = flat >> shift;      // row
  int j0 = flat & colMask;    // first col (8 consecutive cols share the row)
  unsigned step = (unsigned)(2 * i + 1) & mask4N;
  unsigned r = ((unsigned)j0 * (unsigned)(2 * i + 1)) & mask4N;
  u16x8 oc, os;
#pragma unroll
  for (int t = 0; t < 8; t++) {
    float ang = (float)r * angScale;
    float s, c;
    __sincosf(ang, &s, &c);
    oc[t] = f2bf(c);
    os[t] = f2bf(s);
    r = (r + step) & mask4N;
  }
  Ccos[idx] = oc;
  S[idx] = os;
}

// ---- bt-GEMM: C[m,n] = sum_k A[m,k] * Bt[n,k], bf16 in, fp32 acc ----
// BM=BN=128, BK=32, 256 threads (4 waves, 2x2 wave grid, 64x64 per wave).
// Staging via global_load_lds width=16: wave w stages 1KB chunks {w, w+4}
// of As and Bs (16 rows each; LDS rows are 64B, contiguous, unpadded —
// dst = wave-uniform base + lane*16 lands exactly on row 16c + lane/4,
// col (lane&3)*8).
template <bool OUT_BF16>
__global__ __launch_bounds__(256, 2) void btgemm_kernel(
    const unsigned short* __restrict__ A,   // [Mdim x K] bf16 row-major
    const unsigned short* __restrict__ Bt,  // [Ndim x K] bf16 row-major
    void* __restrict__ C,                   // [Mdim x Ndim]
    int Ndim, int K) {
  __shared__ unsigned short As[128 * 32];
  __shared__ unsigned short Bs[128 * 32];

  const int tid = threadIdx.x;
  const int m0 = blockIdx.y * 128;
  const int n0 = blockIdx.x * 128;

  const int wave = tid >> 6;
  const int lane = tid & 63;
  const int wm = (wave & 1) * 64;
  const int wn = (wave >> 1) * 64;
  const int l16 = lane & 15;
  const int quad = lane >> 4;

  f32x4 acc[4][4];
#pragma unroll
  for (int i = 0; i < 4; i++)
#pragma unroll
    for (int j = 0; j < 4; j++) acc[i][j] = f32x4{0.f, 0.f, 0.f, 0.f};

  // staging source addresses (per-lane); chunk w rows 16w.., chunk w+4 rows 64+16w..
  const int rs0 = wave * 16 + (lane >> 2);
  const int rs1 = 64 + rs0;
  const int cs = (lane & 3) * 8;
  const unsigned short* Ag0 = A + (size_t)(m0 + rs0) * K + cs;
  const unsigned short* Ag1 = A + (size_t)(m0 + rs1) * K + cs;
  const unsigned short* Bg0 = Bt + (size_t)(n0 + rs0) * K + cs;
  const unsigned short* Bg1 = Bt + (size_t)(n0 + rs1) * K + cs;
  unsigned short* Al0 = As + wave * 512;          // 1KB chunks
  unsigned short* Al1 = As + 2048 + wave * 512;
  unsigned short* Bl0 = Bs + wave * 512;
  unsigned short* Bl1 = Bs + 2048 + wave * 512;

  for (int k0 = 0; k0 < K; k0 += 32) {
    __builtin_amdgcn_global_load_lds(
        (const __attribute__((address_space(1))) void*)(Ag0 + k0),
        (__attribute__((address_space(3))) void*)Al0, 16, 0, 0);
    __builtin_amdgcn_global_load_lds(
        (const __attribute__((address_space(1))) void*)(Ag1 + k0),
        (__attribute__((address_space(3))) void*)Al1, 16, 0, 0);
    __builtin_amdgcn_global_load_lds(
        (const __attribute__((address_space(1))) void*)(Bg0 + k0),
        (__attribute__((address_space(3))) void*)Bl0, 16, 0, 0);
    __builtin_amdgcn_global_load_lds(
        (const __attribute__((address_space(1))) void*)(Bg1 + k0),
        (__attribute__((address_space(3))) void*)Bl1, 16, 0, 0);
    __syncthreads();  // drains vmcnt -> staged data visible

    bf16x8 af[4], bfr[4];
#pragma unroll
    for (int i = 0; i < 4; i++) {
      af[i]  = *(const bf16x8*)(As + (wm + i * 16 + l16) * 32 + quad * 8);
      bfr[i] = *(const bf16x8*)(Bs + (wn + i * 16 + l16) * 32 + quad * 8);
    }
#pragma unroll
    for (int i = 0; i < 4; i++)
#pragma unroll
      for (int j = 0; j < 4; j++)
        acc[i][j] = __builtin_amdgcn_mfma_f32_16x16x32_bf16(af[i], bfr[j],
                                                            acc[i][j], 0, 0, 0);
    __syncthreads();  // all ds_reads done before next iter overwrites LDS
  }

  // epilogue: D row = quad*4 + reg, col = lane&15
#pragma unroll
  for (int i = 0; i < 4; i++) {
#pragma unroll
    for (int j = 0; j < 4; j++) {
      int col = n0 + wn + j * 16 + l16;
      int rowb = m0 + wm + i * 16 + quad * 4;
#pragma unroll
      for (int r = 0; r < 4; r++) {
        float v = acc[i][j][r];
        if (OUT_BF16)
          ((unsigned short*)C)[(size_t)(rowb + r) * Ndim + col] = f2bf(v);
        else
          ((float*)C)[(size_t)(rowb + r) * Ndim + col] = v;
      }
    }
  }
}

extern "C" void kernel_launch(void* const* d_in, const int* in_sizes, int n_in,
                              void* d_out, int out_size, void* d_ws,
                              size_t ws_size, hipStream_t stream) {
  const float* x = (const float*)d_in[0];
  const int M = in_sizes[1] / 2;  // expkM is [M,2]
  const int N = in_sizes[2] / 2;  // expkN is [N,2]
  const size_t MN = (size_t)M * N;

  // workspace: xb | Ccos | S | tT  (bf16 each) = 4 * M*N*2 bytes = 128 MB
  unsigned short* xb   = (unsigned short*)d_ws;
  unsigned short* Ccos = xb + MN;
  unsigned short* S    = Ccos + MN;
  unsigned short* tT   = S + MN;

  // 0a: x -> bf16
  int n8 = (int)(MN / 8);
  convert_kernel<<<(n8 + 255) / 256, 256, 0, stream>>>((const f32x4*)x,
                                                       (u16x8*)xb, n8);

  // 0b: transform matrices (M == N == 4096 here; same angle tables)
  int shift = 0;
  while ((1 << shift) < N) shift++;
  float angScale = (float)(3.14159265358979323846 / (2.0 * (double)N));
  gen_mats_kernel<<<(int)(MN / 8 / 256), 256, 0, stream>>>(
      (u16x8*)Ccos, (u16x8*)S, N - 1, shift, (unsigned)(4 * N - 1), angScale);

  // stage 1: tT[v,p] = sum_q C[v,q]*xb[p,q]   -> bf16 [N x M]
  dim3 blk(256);
  dim3 g1(M / 128, N / 128);
  btgemm_kernel<true><<<g1, blk, 0, stream>>>(Ccos, xb, tT, M, N);

  // stage 2: y[u,v] = sum_p S[u,p]*tT[v,p]    -> fp32 [M x N]
  dim3 g2(N / 128, M / 128);
  btgemm_kernel<false><<<g2, blk, 0, stream>>>(S, tT, d_out, N, M);
}

// Round 3
// 321.812 us; speedup vs baseline: 1.4129x; 1.2937x over previous
//
#include <hip/hip_runtime.h>
#include <hip/hip_bf16.h>
#include <stdint.h>
#include <cmath>

// IDXST_IDCT on MI355X: y = S · x · C^T with
//   C[v,q] = cos(pi*q*(2v+1)/(2N)),  S[u,p] = sin(pi*p*(2u+1)/(2M))
// Butterfly decomposition (halves GEMM FLOPs):
//   C[N-1-v,q] = (-1)^q C[v,q]  ->  t[v]=E+O, t[N-1-v]=E-O
//   S[M-1-u,p] = -(-1)^p S[u,p] ->  y[u]=E2+O2, y[M-1-u]=O2-E2
// where E/O are half-K GEMMs over even/odd columns.

typedef __attribute__((ext_vector_type(4))) float f32x4;
typedef __attribute__((ext_vector_type(8))) unsigned short u16x8;
typedef __attribute__((ext_vector_type(8))) __bf16 bf16x8;

__device__ __forceinline__ unsigned short f2bf(float f) {
  union { float f; unsigned u; } v; v.f = f;
  unsigned u = v.u + 0x7fffu + ((v.u >> 16) & 1u);  // RNE
  return (unsigned short)(u >> 16);
}
__device__ __forceinline__ float bf2f(unsigned short h) {
  union { unsigned u; float f; } v; v.u = ((unsigned)h) << 16;
  return v.f;
}

// ---- fp32 -> bf16 convert + even/odd column deinterleave ----
// x: [M x N] fp32; xe/xo: [M x N/2] bf16. 16 floats / thread.
__global__ void convert_deint_kernel(const f32x4* __restrict__ x,
                                     u16x8* __restrict__ xe,
                                     u16x8* __restrict__ xo, int n16) {
  int idx = blockIdx.x * blockDim.x + threadIdx.x;
  if (idx >= n16) return;
  f32x4 a = x[4 * idx], b = x[4 * idx + 1], c = x[4 * idx + 2],
        d = x[4 * idx + 3];
  u16x8 e, o;
  e[0] = f2bf(a[0]); o[0] = f2bf(a[1]); e[1] = f2bf(a[2]); o[1] = f2bf(a[3]);
  e[2] = f2bf(b[0]); o[2] = f2bf(b[1]); e[3] = f2bf(b[2]); o[3] = f2bf(b[3]);
  e[4] = f2bf(c[0]); o[4] = f2bf(c[1]); e[5] = f2bf(c[2]); o[5] = f2bf(c[3]);
  e[6] = f2bf(d[0]); o[6] = f2bf(d[1]); e[7] = f2bf(d[2]); o[7] = f2bf(d[3]);
  xe[idx] = e; xo[idx] = o;
}

// ---- generate half transform matrices [L/2 x L/2] bf16 ----
// Pe[i,j] = f(pi*(2j)(2i+1)/(2L)), Po[i,j] = f(pi*(2j+1)(2i+1)/(2L)),
// f = sin or cos. r computed mod 4L (exact in u32; power of two).
__global__ void gen_half_kernel(u16x8* __restrict__ Pe, u16x8* __restrict__ Po,
                                int isSin, int jshift, int jmask,
                                unsigned mask4L, float sc) {
  int idx = blockIdx.x * blockDim.x + threadIdx.x;
  int i = idx >> jshift;           // row
  int jb = (idx & jmask) * 8;      // first col
  unsigned tp = 2u * (unsigned)i + 1u;
  unsigned re = (2u * (unsigned)jb * tp) & mask4L;
  unsigned ro = (re + tp) & mask4L;
  unsigned step = (2u * tp) & mask4L;
  u16x8 pe, po;
#pragma unroll
  for (int t = 0; t < 8; t++) {
    float se_, ce_, so_, co_;
    __sincosf((float)re * sc, &se_, &ce_);
    __sincosf((float)ro * sc, &so_, &co_);
    pe[t] = f2bf(isSin ? se_ : ce_);
    po[t] = f2bf(isSin ? so_ : co_);
    re = (re + step) & mask4L;
    ro = (ro + step) & mask4L;
  }
  Pe[idx] = pe;
  Po[idx] = po;
}

// ---- bt-GEMM: C[m,n] = sum_k A[m,k] * Bt[n,k], bf16 in, fp32 acc ----
// BM=BN=128, BK=32, 256 threads (4 waves). blockIdx.z selects (A,B,C) set.
// Staging via global_load_lds width=16 (wave-uniform base + lane*16).
template <bool OUT_BF16>
__global__ __launch_bounds__(256, 2) void btgemm_kernel(
    const unsigned short* __restrict__ A0,
    const unsigned short* __restrict__ A1,
    const unsigned short* __restrict__ B0,
    const unsigned short* __restrict__ B1,
    void* __restrict__ C0v, void* __restrict__ C1v, int Ndim, int K) {
  __shared__ unsigned short As[128 * 32];
  __shared__ unsigned short Bs[128 * 32];

  const unsigned short* A = blockIdx.z ? A1 : A0;
  const unsigned short* Bt = blockIdx.z ? B1 : B0;
  void* C = blockIdx.z ? C1v : C0v;

  const int tid = threadIdx.x;
  const int m0 = blockIdx.y * 128;
  const int n0 = blockIdx.x * 128;

  const int wave = tid >> 6;
  const int lane = tid & 63;
  const int wm = (wave & 1) * 64;
  const int wn = (wave >> 1) * 64;
  const int l16 = lane & 15;
  const int quad = lane >> 4;

  f32x4 acc[4][4];
#pragma unroll
  for (int i = 0; i < 4; i++)
#pragma unroll
    for (int j = 0; j < 4; j++) acc[i][j] = f32x4{0.f, 0.f, 0.f, 0.f};

  const int rs0 = wave * 16 + (lane >> 2);
  const int rs1 = 64 + rs0;
  const int cs = (lane & 3) * 8;
  const unsigned short* Ag0 = A + (size_t)(m0 + rs0) * K + cs;
  const unsigned short* Ag1 = A + (size_t)(m0 + rs1) * K + cs;
  const unsigned short* Bg0 = Bt + (size_t)(n0 + rs0) * K + cs;
  const unsigned short* Bg1 = Bt + (size_t)(n0 + rs1) * K + cs;
  unsigned short* Al0 = As + wave * 512;
  unsigned short* Al1 = As + 2048 + wave * 512;
  unsigned short* Bl0 = Bs + wave * 512;
  unsigned short* Bl1 = Bs + 2048 + wave * 512;

  for (int k0 = 0; k0 < K; k0 += 32) {
    __builtin_amdgcn_global_load_lds(
        (const __attribute__((address_space(1))) void*)(Ag0 + k0),
        (__attribute__((address_space(3))) void*)Al0, 16, 0, 0);
    __builtin_amdgcn_global_load_lds(
        (const __attribute__((address_space(1))) void*)(Ag1 + k0),
        (__attribute__((address_space(3))) void*)Al1, 16, 0, 0);
    __builtin_amdgcn_global_load_lds(
        (const __attribute__((address_space(1))) void*)(Bg0 + k0),
        (__attribute__((address_space(3))) void*)Bl0, 16, 0, 0);
    __builtin_amdgcn_global_load_lds(
        (const __attribute__((address_space(1))) void*)(Bg1 + k0),
        (__attribute__((address_space(3))) void*)Bl1, 16, 0, 0);
    __syncthreads();

    bf16x8 af[4], bfr[4];
#pragma unroll
    for (int i = 0; i < 4; i++) {
      af[i]  = *(const bf16x8*)(As + (wm + i * 16 + l16) * 32 + quad * 8);
      bfr[i] = *(const bf16x8*)(Bs + (wn + i * 16 + l16) * 32 + quad * 8);
    }
#pragma unroll
    for (int i = 0; i < 4; i++)
#pragma unroll
      for (int j = 0; j < 4; j++)
        acc[i][j] = __builtin_amdgcn_mfma_f32_16x16x32_bf16(af[i], bfr[j],
                                                            acc[i][j], 0, 0, 0);
    __syncthreads();
  }

  // epilogue: D row = quad*4 + reg, col = lane&15
#pragma unroll
  for (int i = 0; i < 4; i++) {
#pragma unroll
    for (int j = 0; j < 4; j++) {
      int col = n0 + wn + j * 16 + l16;
      int rowb = m0 + wm + i * 16 + quad * 4;
#pragma unroll
      for (int r = 0; r < 4; r++) {
        float v = acc[i][j][r];
        if (OUT_BF16)
          ((unsigned short*)C)[(size_t)(rowb + r) * Ndim + col] = f2bf(v);
        else
          ((float*)C)[(size_t)(rowb + r) * Ndim + col] = v;
      }
    }
  }
}

// ---- butterfly 1: E1,O1 [N/2 x M] bf16 -> tTe,tTo [N x M/2] bf16 ----
// t[v,p]=E+O, t[N-1-v,p]=E-O; simultaneously deinterleave by p parity.
// 16 p-cols per thread.
__global__ void bfly1_kernel(const u16x8* __restrict__ E1,
                             const u16x8* __restrict__ O1,
                             u16x8* __restrict__ tTe, u16x8* __restrict__ tTo,
                             int pshift, int pmask, int Nrows, int Mh8) {
  int idx = blockIdx.x * blockDim.x + threadIdx.x;
  int v = idx >> pshift;            // row of E1 (0..N/2)
  int pu = idx & pmask;             // p-chunk within row (16 cols each)
  u16x8 e0 = E1[2 * idx], e1 = E1[2 * idx + 1];
  u16x8 o0 = O1[2 * idx], o1 = O1[2 * idx + 1];
  u16x8 tet, tot, teb, tob;
#pragma unroll
  for (int k = 0; k < 4; k++) {
    float ee = bf2f(e0[2 * k]), eo = bf2f(e0[2 * k + 1]);
    float oe = bf2f(o0[2 * k]), oo = bf2f(o0[2 * k + 1]);
    tet[k] = f2bf(ee + oe); tot[k] = f2bf(eo + oo);
    teb[k] = f2bf(ee - oe); tob[k] = f2bf(eo - oo);
  }
#pragma unroll
  for (int k = 0; k < 4; k++) {
    float ee = bf2f(e1[2 * k]), eo = bf2f(e1[2 * k + 1]);
    float oe = bf2f(o1[2 * k]), oo = bf2f(o1[2 * k + 1]);
    tet[4 + k] = f2bf(ee + oe); tot[4 + k] = f2bf(eo + oo);
    teb[4 + k] = f2bf(ee - oe); tob[4 + k] = f2bf(eo - oo);
  }
  tTe[idx] = tet;
  tTo[idx] = tot;
  int idxb = (Nrows - 1 - v) * Mh8 + pu;
  tTe[idxb] = teb;
  tTo[idxb] = tob;
}

// ---- butterfly 2: E2,O2 [M/2 x N] fp32 -> y [M x N] fp32 ----
// y[u]=E2+O2, y[M-1-u]=O2-E2. 16 floats per thread.
__global__ void bfly2_kernel(const f32x4* __restrict__ E2,
                             const f32x4* __restrict__ O2,
                             f32x4* __restrict__ y, int vshift, int vmask,
                             int Mrows, int N4) {
  int idx = blockIdx.x * blockDim.x + threadIdx.x;
  int u = idx >> vshift;
  int vu = (idx & vmask) * 4;       // f32x4 units within row
  int baseb = (Mrows - 1 - u) * N4 + vu;
  int baset = u * N4 + vu;
#pragma unroll
  for (int t = 0; t < 4; t++) {
    f32x4 e = E2[4 * idx + t];
    f32x4 o = O2[4 * idx + t];
    y[baset + t] = e + o;
    y[baseb + t] = o - e;
  }
}

extern "C" void kernel_launch(void* const* d_in, const int* in_sizes, int n_in,
                              void* d_out, int out_size, void* d_ws,
                              size_t ws_size, hipStream_t stream) {
  const float* x = (const float*)d_in[0];
  const int M = in_sizes[1] / 2;  // expkM is [M,2]
  const int N = in_sizes[2] / 2;  // expkN is [N,2]
  const size_t MN = (size_t)M * N;

  // workspace layout (u16 units), 3.5*MN u16 = 117 MB @4096:
  //  [0, MN/2)        xe   [M x N/2]      (later E2 fp32 [M/2 x N])
  //  [MN/2, MN)       xo   [M x N/2]
  //  [MN, MN*5/4)     Ae   (Ce, later Se) [N/2 x N/2]
  //  [MN*5/4, MN*3/2) Ao   (Co, later So)
  //  [MN*3/2, MN*2)   E1   [N/2 x M]      (later O2 fp32, spans E1+O1)
  //  [MN*2, MN*5/2)   O1   [N/2 x M]
  //  [MN*5/2, MN*3)   tTe  [N x M/2]
  //  [MN*3, MN*7/2)   tTo  [N x M/2]
  unsigned short* ws = (unsigned short*)d_ws;
  unsigned short* xe = ws;
  unsigned short* xo = ws + MN / 2;
  unsigned short* Ae = ws + MN;
  unsigned short* Ao = ws + MN + MN / 4;
  unsigned short* E1 = ws + MN * 3 / 2;
  unsigned short* O1 = ws + MN * 2;
  unsigned short* tTe = ws + MN * 5 / 2;
  unsigned short* tTo = ws + MN * 3;
  float* E2 = (float*)ws;
  float* O2 = (float*)(ws + MN * 3 / 2);

  int shiftN = 0; while ((1 << shiftN) < N) shiftN++;
  int shiftM = 0; while ((1 << shiftM) < M) shiftM++;

  // 1: convert + deinterleave x columns by parity
  int n16 = (int)(MN / 16);
  convert_deint_kernel<<<(n16 + 255) / 256, 256, 0, stream>>>(
      (const f32x4*)x, (u16x8*)xe, (u16x8*)xo, n16);

  // 2: Ce, Co (cos, modulus 4N)
  {
    int threads = (N / 2) * (N / 2) / 8;
    gen_half_kernel<<<threads / 256, 256, 0, stream>>>(
        (u16x8*)Ae, (u16x8*)Ao, 0, shiftN - 4, (N / 16) - 1,
        (unsigned)(4 * N - 1), (float)(3.14159265358979323846 / (2.0 * N)));
  }

  // 3: stage-1 half GEMMs: E1 = Ce·xe^T, O1 = Co·xo^T  (out bf16, stride M)
  btgemm_kernel<true><<<dim3(M / 128, (N / 2) / 128, 2), 256, 0, stream>>>(
      Ae, Ao, xe, xo, E1, O1, M, N / 2);

  // 4: butterfly + p-parity deinterleave -> tTe, tTo
  {
    int threads = (int)(MN / 32);  // (N/2 rows) x (M/16 chunks)
    bfly1_kernel<<<threads / 256, 256, 0, stream>>>(
        (const u16x8*)E1, (const u16x8*)O1, (u16x8*)tTe, (u16x8*)tTo,
        shiftM - 4, (M / 16) - 1, N, M / 16);
  }

  // 5: Se, So (sin, modulus 4M) over Ae/Ao
  {
    int threads = (M / 2) * (M / 2) / 8;
    gen_half_kernel<<<threads / 256, 256, 0, stream>>>(
        (u16x8*)Ae, (u16x8*)Ao, 1, shiftM - 4, (M / 16) - 1,
        (unsigned)(4 * M - 1), (float)(3.14159265358979323846 / (2.0 * M)));
  }

  // 6: stage-2 half GEMMs: E2 = Se·tTe^T, O2 = So·tTo^T (out fp32, stride N)
  btgemm_kernel<false><<<dim3(N / 128, (M / 2) / 128, 2), 256, 0, stream>>>(
      Ae, Ao, tTe, tTo, E2, O2, N, M / 2);

  // 7: final butterfly -> y
  {
    int threads = (int)(MN / 32);  // (M/2 rows) x (N/16 chunks)
    bfly2_kernel<<<threads / 256, 256, 0, stream>>>(
        (const f32x4*)E2, (const f32x4*)O2, (f32x4*)d_out, shiftN - 4,
        (N / 16) - 1, M, N / 4);
  }
}